// Round 3
// baseline (398.683 us; speedup 1.0000x reference)
//
#include <hip/hip_runtime.h>
#include <hip/hip_bf16.h>
#include <stdint.h>

// Problem constants (fixed by the reference): B=4, S=8192, IN=1024, OUT=1024
#define M_TOT  32768
#define K_DIM  1024
#define N_DIM  1024

typedef short bf16x8 __attribute__((ext_vector_type(8)));   // 8 bf16 = 4 VGPRs
typedef float f32x4  __attribute__((ext_vector_type(4)));

#define AS1(p) ((__attribute__((address_space(1))) void*)(p))
#define AS3(p) ((__attribute__((address_space(3))) void*)(p))

__device__ __forceinline__ uint32_t packbf2(float a, float b) {
    __hip_bfloat162 h = __float22bfloat162_rn(make_float2(a, b));
    union { __hip_bfloat162 h; uint32_t u; } cvt;
    cvt.h = h;
    return cvt.u;
}

// ---------- prep: block 0 = deterministic compaction; blocks 1..256 = W cvt ----------
__global__ __launch_bounds__(1024) void prep_kernel(
        const int* __restrict__ mask,
        const float* __restrict__ wv, const float* __restrict__ wt,
        ushort* __restrict__ dv, ushort* __restrict__ dt,
        int* __restrict__ V, int* __restrict__ T, int* __restrict__ cnt) {
    if (blockIdx.x != 0) {
        // weight fp32 -> bf16: 2*1024*1024 elems over 256 blocks x 1024 thr x 8
        int b = blockIdx.x - 1;                       // 0..255
        int u = b * 8192 + threadIdx.x * 8;
        const float* src; ushort* dst; int off;
        if (u < 1048576) { src = wv; dst = dv; off = u; }
        else             { src = wt; dst = dt; off = u - 1048576; }
        float4 a0 = *(const float4*)(src + off);
        float4 a1 = *(const float4*)(src + off + 4);
        uint4 p;
        p.x = packbf2(a0.x, a0.y);
        p.y = packbf2(a0.z, a0.w);
        p.z = packbf2(a1.x, a1.y);
        p.w = packbf2(a1.z, a1.w);
        *(uint4*)(dst + off) = p;
        return;
    }

    // ---- block 0: single-block compaction (NO atomics), 1024 threads ----
    const int tid  = threadIdx.x;
    const int lane = tid & 63;
    const int wv_  = tid >> 6;

    const int4* mp = (const int4*)mask + tid * 8;
    uint32_t bits = 0;
#pragma unroll
    for (int i = 0; i < 8; ++i) {
        int4 v = mp[i];
        bits |= (uint32_t)(v.x != 0) << (i * 4 + 0);
        bits |= (uint32_t)(v.y != 0) << (i * 4 + 1);
        bits |= (uint32_t)(v.z != 0) << (i * 4 + 2);
        bits |= (uint32_t)(v.w != 0) << (i * 4 + 3);
    }
    int vcnt = __popc(bits);

    int incl = vcnt;
#pragma unroll
    for (int d = 1; d < 64; d <<= 1) {
        int y = __shfl_up(incl, d);
        if (lane >= d) incl += y;
    }
    __shared__ int wsum[16], wexcl[16], totv_s;
    if (lane == 63) wsum[wv_] = incl;
    __syncthreads();
    if (tid == 0) {
        int s = 0;
#pragma unroll
        for (int i = 0; i < 16; ++i) { wexcl[i] = s; s += wsum[i]; }
        totv_s = s;
    }
    __syncthreads();
    const int vexcl = wexcl[wv_] + incl - vcnt;
    int vbase = vexcl;
    int tbase = tid * 32 - vexcl;

#pragma unroll
    for (int j = 0; j < 32; ++j) {
        int e = tid * 32 + j;
        if ((bits >> j) & 1u) V[vbase++] = e;
        else                  T[tbase++] = e;
    }

    const int Nv = totv_s, Nt = M_TOT - totv_s;
    if (tid == 0) { cnt[0] = Nv; cnt[1] = Nt; }

    __syncthreads();
    const int NBv = (Nv + 127) >> 7, NBt = (Nt + 127) >> 7;
    for (int p = Nv + tid; p < NBv * 128; p += 1024) V[p] = -1;
    for (int p = Nt + tid; p < NBt * 128; p += 1024) T[p] = -1;
}

// ---------- gathered-row 128x128x(BK=64) bf16 MFMA GEMM ----------
// A: fp32 x loaded to regs (fused cvt), packed bf16, ds_write w/ XOR swizzle.
// B: bf16 weights via global_load_lds width=16.
// BOTH tiles double-buffered -> ONE __syncthreads per K-step; B-DMA(t+1) and
// A-loads(t+1) are issued before the MFMA phase of t and fly under it.
// No inline asm: compiler owns all waitcnts (sync drains a DMA that has had
// the whole MFMA phase to complete).
__global__ __launch_bounds__(256) void gemm_kernel(
        const float*  __restrict__ x,
        const ushort* __restrict__ Wv,
        const ushort* __restrict__ Wt,
        const int*    __restrict__ V,
        const int*    __restrict__ T,
        const int*    __restrict__ cnt,
        float*        __restrict__ out) {
    // chunk layout: chunk (row, kc) lives at LDS chunk index row*8 + (kc ^ (row&7))
    __shared__ ushort sA[2][128 * 64];     // 32 KB
    __shared__ ushort sB[2][128 * 64];     // 32 KB

    const int tid  = threadIdx.x;
    const int lane = tid & 63;
    const int w    = tid >> 6;

    // XCD-sticky swizzle: all 8 bn-blocks of one bm share blockIdx%8
    const int kx = blockIdx.x & 7;
    const int bn = (blockIdx.x >> 3) & 7;
    const int gk = blockIdx.x >> 6;
    const int bm = gk * 8 + kx;

    const int Nv  = cnt[0];
    const int Nt  = cnt[1];
    const int NBv = (Nv + 127) >> 7;
    const int NBt = (Nt + 127) >> 7;
    if (bm >= NBv + NBt) return;

    const bool vis = (bm < NBv);
    const int*    rowbase = vis ? (V + (size_t)bm * 128)
                                : (T + (size_t)(bm - NBv) * 128);
    const ushort* W       = vis ? Wv : Wt;
    const int n0 = bn * 128;

    // staging assignment: thread covers rows r*32+trow, 16B-bf16-chunk kcb;
    // swizzled LDS dest collapses to linear chunk (r*256 + tid).
    const int trow = tid >> 3;
    const int kcb  = (tid & 7) ^ (trow & 7);
    const float*  apf[4];
    const ushort* wp[4];
#pragma unroll
    for (int r = 0; r < 4; ++r) {
        int rr = rowbase[r * 32 + trow];
        if (rr < 0) rr = 0;                      // sentinel row: safe addr, masked at store
        apf[r] = x + (size_t)rr * K_DIM + kcb * 8;
        wp[r]  = W + (size_t)(n0 + r * 32 + trow) * K_DIM + kcb * 8;
    }

    // fragment read offsets (bytes, within one 8 KB tile)
    const int ml   = lane & 15;
    const int quad = lane >> 4;
    const int wm = (w & 1) * 64;
    const int wn = (w >> 1) * 64;
    uint32_t aoff[2][4], boff[2][4];
#pragma unroll
    for (int ks = 0; ks < 2; ++ks) {
        int kxr = (ks * 4 + quad) ^ (ml & 7);
#pragma unroll
        for (int t = 0; t < 4; ++t) {
            aoff[ks][t] = (uint32_t)(((wm + t * 16 + ml) * 8 + kxr) * 16);
            boff[ks][t] = (uint32_t)(((wn + t * 16 + ml) * 8 + kxr) * 16);
        }
    }

    f32x4 acc[4][4];
#pragma unroll
    for (int i = 0; i < 4; ++i)
#pragma unroll
        for (int j = 0; j < 4; ++j) {
            f32x4 z = {0.f, 0.f, 0.f, 0.f};
            acc[i][j] = z;
        }

    char* sAb[2] = { (char*)sA[0], (char*)sA[1] };
    char* sBb[2] = { (char*)sB[0], (char*)sB[1] };

    // prologue: B(0) DMA -> sB[0]; A(0) -> regs -> pack -> sA[0]
#pragma unroll
    for (int r = 0; r < 4; ++r) {
        char* lb = sBb[0] + (size_t)(r * 256 + w * 64) * 16;
        __builtin_amdgcn_global_load_lds(AS1(wp[r]), AS3(lb), 16, 0, 0);
    }
    float4 a[8];
#pragma unroll
    for (int r = 0; r < 4; ++r) {
        a[r * 2]     = *(const float4*)(apf[r]);
        a[r * 2 + 1] = *(const float4*)(apf[r] + 4);
    }
#pragma unroll
    for (int r = 0; r < 4; ++r) {
        uint4 p;
        p.x = packbf2(a[r * 2].x,     a[r * 2].y);
        p.y = packbf2(a[r * 2].z,     a[r * 2].w);
        p.z = packbf2(a[r * 2 + 1].x, a[r * 2 + 1].y);
        p.w = packbf2(a[r * 2 + 1].z, a[r * 2 + 1].w);
        *(uint4*)(sAb[0] + (size_t)(r * 256 + tid) * 16) = p;
    }
    __syncthreads();

#pragma unroll
    for (int kt = 0; kt < 16; ++kt) {
        const int k0  = kt * 64;
        const int cur = kt & 1;
        const int nxt = cur ^ 1;

        if (kt < 15) {
            // B(t+1) DMA + A(t+1) reg loads fly under the MFMA phase below
#pragma unroll
            for (int r = 0; r < 4; ++r) {
                char* lb = sBb[nxt] + (size_t)(r * 256 + w * 64) * 16;
                __builtin_amdgcn_global_load_lds(AS1(wp[r] + k0 + 64), AS3(lb), 16, 0, 0);
            }
#pragma unroll
            for (int r = 0; r < 4; ++r) {
                a[r * 2]     = *(const float4*)(apf[r] + k0 + 64);
                a[r * 2 + 1] = *(const float4*)(apf[r] + k0 + 68);
            }
        }

#pragma unroll
        for (int ks = 0; ks < 2; ++ks) {
            bf16x8 af[4], bfr[4];
#pragma unroll
            for (int t = 0; t < 4; ++t) af[t]  = *(const bf16x8*)(sAb[cur] + aoff[ks][t]);
#pragma unroll
            for (int t = 0; t < 4; ++t) bfr[t] = *(const bf16x8*)(sBb[cur] + boff[ks][t]);
#pragma unroll
            for (int tm = 0; tm < 4; ++tm)
#pragma unroll
                for (int tn = 0; tn < 4; ++tn)
                    acc[tm][tn] = __builtin_amdgcn_mfma_f32_16x16x32_bf16(
                        af[tm], bfr[tn], acc[tm][tn], 0, 0, 0);
        }

        if (kt < 15) {
            // pack A(t+1) -> sA[nxt] (compiler waits the reg loads via dep)
#pragma unroll
            for (int r = 0; r < 4; ++r) {
                uint4 p;
                p.x = packbf2(a[r * 2].x,     a[r * 2].y);
                p.y = packbf2(a[r * 2].z,     a[r * 2].w);
                p.z = packbf2(a[r * 2 + 1].x, a[r * 2 + 1].y);
                p.w = packbf2(a[r * 2 + 1].z, a[r * 2 + 1].w);
                *(uint4*)(sAb[nxt] + (size_t)(r * 256 + tid) * 16) = p;
            }
        }
        __syncthreads();   // one barrier per K-step: drains DMA + A-writes
    }

    // epilogue: scatter rows via index list (C/D: col=lane&15, row=quad*4+reg)
#pragma unroll
    for (int tm = 0; tm < 4; ++tm) {
        const int rb = wm + tm * 16 + quad * 4;
        int sr0 = rowbase[rb + 0];
        int sr1 = rowbase[rb + 1];
        int sr2 = rowbase[rb + 2];
        int sr3 = rowbase[rb + 3];
#pragma unroll
        for (int tn = 0; tn < 4; ++tn) {
            const int col = n0 + wn + tn * 16 + ml;
            if (sr0 >= 0) out[(size_t)sr0 * N_DIM + col] = acc[tm][tn][0];
            if (sr1 >= 0) out[(size_t)sr1 * N_DIM + col] = acc[tm][tn][1];
            if (sr2 >= 0) out[(size_t)sr2 * N_DIM + col] = acc[tm][tn][2];
            if (sr3 >= 0) out[(size_t)sr3 * N_DIM + col] = acc[tm][tn][3];
        }
    }
}

// ws layout:
//   [0, 2MB)        W_v bf16
//   [2MB, 4MB)      W_t bf16
//   [4MB, +128KB)   V index list (32768 int)
//   [...,+128KB)    T index list (32768 int)
//   [...,+8B)       counters {Nv, Nt}
extern "C" void kernel_launch(void* const* d_in, const int* in_sizes, int n_in,
                              void* d_out, int out_size, void* d_ws, size_t ws_size,
                              hipStream_t stream) {
    const float* x    = (const float*)d_in[0];
    const int*   mask = (const int*)d_in[1];
    const float* Wv   = (const float*)d_in[2];
    const float* Wt   = (const float*)d_in[3];
    float* out = (float*)d_out;

    char* ws = (char*)d_ws;
    ushort* dWv = (ushort*)(ws);
    ushort* dWt = (ushort*)(ws + (1 << 21));
    int* V   = (int*)(ws + (1 << 22));
    int* T   = V + 32768;
    int* cnt = T + 32768;

    prep_kernel<<<257, 1024, 0, stream>>>(mask, Wv, Wt, dWv, dWt, V, T, cnt);
    // grid: bm = gk*8 + (blockIdx&7) must reach ~258 -> gk up to 32 -> 33*64 blocks
    gemm_kernel<<<33 * 64, 256, 0, stream>>>(x, dWv, dWt, V, T, cnt, out);
}

// Round 4
// 341.456 us; speedup vs baseline: 1.1676x; 1.1676x over previous
//
#include <hip/hip_runtime.h>
#include <hip/hip_bf16.h>
#include <stdint.h>

// Problem constants (fixed by the reference): B=4, S=8192, IN=1024, OUT=1024
#define M_TOT  32768
#define K_DIM  1024
#define N_DIM  1024

typedef short bf16x8 __attribute__((ext_vector_type(8)));   // 8 bf16 = 4 VGPRs
typedef float f32x4  __attribute__((ext_vector_type(4)));

#define AS1(p) ((__attribute__((address_space(1))) void*)(p))
#define AS3(p) ((__attribute__((address_space(3))) void*)(p))

__device__ __forceinline__ uint32_t packbf2(float a, float b) {
    __hip_bfloat162 h = __float22bfloat162_rn(make_float2(a, b));
    union { __hip_bfloat162 h; uint32_t u; } cvt;
    cvt.h = h;
    return cvt.u;
}

// ---------- prep: ONE launch does compaction (32 blocks) + W cvt (256) + x cvt (4096) ----------
// Block roles: [0,32) compaction, [32,288) W fp32->bf16, [288,4384) x fp32->bf16.
// Compaction is deterministic multi-block with NO cross-block sync: block b
// redundantly popcounts mask[0, b*1024) (128 KB total, L2-resident) to get its
// global V-prefix, then ballot-compacts its own 1024 elements, one store/thread.
__global__ __launch_bounds__(1024) void prep_kernel(
        const float* __restrict__ x,  const int* __restrict__ mask,
        const float* __restrict__ wv, const float* __restrict__ wt,
        ushort* __restrict__ xb, ushort* __restrict__ dv, ushort* __restrict__ dt,
        int* __restrict__ V, int* __restrict__ T, int* __restrict__ cnt) {
    const int b   = blockIdx.x;
    const int tid = threadIdx.x;

    if (b < 32) {
        // ---- compaction: block b owns elements [b*1024, (b+1)*1024) ----
        const int lane = tid & 63;
        const int wv_i = tid >> 6;

        // (1) global V-prefix: popcount of mask[0, b*1024)
        int pre = 0;
        const int nPre4 = b * 256;                    // int4 count
        for (int i = tid; i < nPre4; i += 1024) {
            int4 v = ((const int4*)mask)[i];
            pre += (v.x != 0) + (v.y != 0) + (v.z != 0) + (v.w != 0);
        }
#pragma unroll
        for (int d = 32; d > 0; d >>= 1) pre += __shfl_down(pre, d);
        __shared__ int wsum[16];
        __shared__ int pref_s;
        if (lane == 0) wsum[wv_i] = pre;
        __syncthreads();
        if (tid == 0) {
            int s = 0;
#pragma unroll
            for (int i = 0; i < 16; ++i) s += wsum[i];
            pref_s = s;
        }
        __syncthreads();
        const int prefix_v = pref_s;

        // (2) own element: ballot-compact, one store per thread
        const int e   = b * 1024 + tid;
        const int bit = (mask[e] != 0) ? 1 : 0;
        unsigned long long bal = __ballot(bit);
        const int lexcl = __popcll(bal & ((1ull << lane) - 1ull));
        const int wcnt  = __popcll(bal);
        __shared__ int wc[16];
        if (lane == 0) wc[wv_i] = wcnt;
        __syncthreads();
        int wpre = 0;
        for (int i = 0; i < wv_i; ++i) wpre += wc[i];
        int chunk_tot = 0;
#pragma unroll
        for (int i = 0; i < 16; ++i) chunk_tot += wc[i];
        const int gv = prefix_v + wpre + lexcl;      // V's strictly before e, + self pos
        if (bit) V[gv]     = e;
        else     T[e - gv] = e;

        // (3) block 31: totals + sentinel padding (disjoint positions, no sync needed)
        if (b == 31) {
            const int Nv = prefix_v + chunk_tot;
            const int Nt = M_TOT - Nv;
            if (tid == 0) { cnt[0] = Nv; cnt[1] = Nt; }
            const int NBv = (Nv + 127) >> 7, NBt = (Nt + 127) >> 7;
            for (int p = Nv + tid; p < NBv * 128; p += 1024) V[p] = -1;
            for (int p = Nt + tid; p < NBt * 128; p += 1024) T[p] = -1;
        }
        return;
    }

    if (b < 288) {
        // ---- W fp32 -> bf16: 2*1024*1024 elems over 256 blocks x 1024 thr x 8 ----
        int u = (b - 32) * 8192 + tid * 8;
        const float* src; ushort* dst; int off;
        if (u < 1048576) { src = wv; dst = dv; off = u; }
        else             { src = wt; dst = dt; off = u - 1048576; }
        float4 a0 = *(const float4*)(src + off);
        float4 a1 = *(const float4*)(src + off + 4);
        uint4 p;
        p.x = packbf2(a0.x, a0.y);
        p.y = packbf2(a0.z, a0.w);
        p.z = packbf2(a1.x, a1.y);
        p.w = packbf2(a1.z, a1.w);
        *(uint4*)(dst + off) = p;
        return;
    }

    // ---- x fp32 -> bf16: 33554432 elems over 4096 blocks x 1024 thr x 8 ----
    const int off = (b - 288) * 8192 + tid * 8;
    float4 a0 = *(const float4*)(x + off);
    float4 a1 = *(const float4*)(x + off + 4);
    uint4 p;
    p.x = packbf2(a0.x, a0.y);
    p.y = packbf2(a0.z, a0.w);
    p.z = packbf2(a1.x, a1.y);
    p.w = packbf2(a1.z, a1.w);
    *(uint4*)(xb + off) = p;
}

// ---------- gathered-row 128x128x(BK=64) bf16 MFMA GEMM, all-DMA staging ----------
// (verbatim R0 structure — measured 118 us)
// Each block: 128 rows from one list (ONE weight matrix), full K, 128 cols.
// A and B both staged via global_load_lds width=16 (gather is on the per-lane
// global address; LDS side is uniform base + lane*16).  16B-chunk XOR swizzle.
__global__ __launch_bounds__(256) void gemm_kernel(
        const ushort* __restrict__ xb,
        const ushort* __restrict__ Wv,
        const ushort* __restrict__ Wt,
        const int*    __restrict__ V,
        const int*    __restrict__ T,
        const int*    __restrict__ cnt,
        float*        __restrict__ out) {
    // chunk layout: chunk (row, kc) lives at LDS chunk index row*8 + (kc ^ (row&7))
    __shared__ ushort sA[128 * 64];   // 16 KB
    __shared__ ushort sB[128 * 64];   // 16 KB

    const int tid  = threadIdx.x;
    const int lane = tid & 63;
    const int w    = tid >> 6;

    // XCD-sticky swizzle: all 8 bn-blocks of one bm share blockIdx%8
    const int kx = blockIdx.x & 7;
    const int bn = (blockIdx.x >> 3) & 7;
    const int gk = blockIdx.x >> 6;
    const int bm = gk * 8 + kx;

    const int Nv  = cnt[0];
    const int Nt  = cnt[1];
    const int NBv = (Nv + 127) >> 7;
    const int NBt = (Nt + 127) >> 7;
    if (bm >= NBv + NBt) return;

    const bool vis = (bm < NBv);
    const int*    rowbase = vis ? (V + (size_t)bm * 128)
                                : (T + (size_t)(bm - NBv) * 128);
    const ushort* W       = vis ? Wv : Wt;
    const int n0 = bn * 128;

    // DMA source pointers: lane covers LDS chunk p = r*256+tid ->
    //   row n = r*32 + (tid>>3), chunk kc = (tid&7) ^ (n&7) = (tid&7)^((tid>>3)&7)
    const int trow = tid >> 3;
    const int kcb  = (tid & 7) ^ (trow & 7);
    const ushort* ap[4];
    const ushort* wp[4];
#pragma unroll
    for (int r = 0; r < 4; ++r) {
        int rr = rowbase[r * 32 + trow];
        if (rr < 0) rr = 0;                      // sentinel row: safe addr, masked at store
        ap[r] = xb + (size_t)rr * K_DIM + kcb * 8;
        wp[r] = W + (size_t)(n0 + r * 32 + trow) * K_DIM + kcb * 8;
    }

    // fragment read offsets (bytes)
    const int ml   = lane & 15;
    const int quad = lane >> 4;
    const int wm = (w & 1) * 64;
    const int wn = (w >> 1) * 64;
    uint32_t aoff[2][4], boff[2][4];
#pragma unroll
    for (int ks = 0; ks < 2; ++ks) {
        int kxr = (ks * 4 + quad) ^ (ml & 7);
#pragma unroll
        for (int t = 0; t < 4; ++t) {
            aoff[ks][t] = (uint32_t)(((wm + t * 16 + ml) * 8 + kxr) * 16);
            boff[ks][t] = (uint32_t)(((wn + t * 16 + ml) * 8 + kxr) * 16);
        }
    }

    f32x4 acc[4][4];
#pragma unroll
    for (int i = 0; i < 4; ++i)
#pragma unroll
        for (int j = 0; j < 4; ++j) {
            f32x4 z = {0.f, 0.f, 0.f, 0.f};
            acc[i][j] = z;
        }

    char* sAb = (char*)sA;
    char* sBb = (char*)sB;

    for (int kt = 0; kt < 16; ++kt) {
        const int k0 = kt * 64;
#pragma unroll
        for (int r = 0; r < 4; ++r) {
            char* lb = sBb + (size_t)(r * 256 + w * 64) * 16;   // wave-uniform base
            __builtin_amdgcn_global_load_lds(AS1(wp[r] + k0), AS3(lb), 16, 0, 0);
        }
#pragma unroll
        for (int r = 0; r < 4; ++r) {
            char* la = sAb + (size_t)(r * 256 + w * 64) * 16;
            __builtin_amdgcn_global_load_lds(AS1(ap[r] + k0), AS3(la), 16, 0, 0);
        }
        __syncthreads();   // drains vmcnt (DMA) before frag reads
#pragma unroll
        for (int ks = 0; ks < 2; ++ks) {
            bf16x8 af[4], bf[4];
#pragma unroll
            for (int t = 0; t < 4; ++t) af[t] = *(const bf16x8*)(sAb + aoff[ks][t]);
#pragma unroll
            for (int t = 0; t < 4; ++t) bf[t] = *(const bf16x8*)(sBb + boff[ks][t]);
#pragma unroll
            for (int tm = 0; tm < 4; ++tm)
#pragma unroll
                for (int tn = 0; tn < 4; ++tn)
                    acc[tm][tn] = __builtin_amdgcn_mfma_f32_16x16x32_bf16(
                        af[tm], bf[tn], acc[tm][tn], 0, 0, 0);
        }
        __syncthreads();
    }

    // epilogue: scatter rows via index list (C/D: col=lane&15, row=quad*4+reg)
    // lists are sorted -> stores are near-coalesced
#pragma unroll
    for (int tm = 0; tm < 4; ++tm) {
        const int rb = wm + tm * 16 + quad * 4;
        int sr0 = rowbase[rb + 0];
        int sr1 = rowbase[rb + 1];
        int sr2 = rowbase[rb + 2];
        int sr3 = rowbase[rb + 3];
#pragma unroll
        for (int tn = 0; tn < 4; ++tn) {
            const int col = n0 + wn + tn * 16 + ml;
            if (sr0 >= 0) out[(size_t)sr0 * N_DIM + col] = acc[tm][tn][0];
            if (sr1 >= 0) out[(size_t)sr1 * N_DIM + col] = acc[tm][tn][1];
            if (sr2 >= 0) out[(size_t)sr2 * N_DIM + col] = acc[tm][tn][2];
            if (sr3 >= 0) out[(size_t)sr3 * N_DIM + col] = acc[tm][tn][3];
        }
    }
}

// ws layout:
//   [0, 64MB)          x bf16 (32768 x 1024)
//   [64MB, 66MB)       W_v bf16
//   [66MB, 68MB)       W_t bf16
//   [68MB, +128KB)     V index list (32768 int)
//   [..,   +128KB)     T index list (32768 int)
//   [..,   +8B)        counters {Nv, Nt}
extern "C" void kernel_launch(void* const* d_in, const int* in_sizes, int n_in,
                              void* d_out, int out_size, void* d_ws, size_t ws_size,
                              hipStream_t stream) {
    const float* x    = (const float*)d_in[0];
    const int*   mask = (const int*)d_in[1];
    const float* Wv   = (const float*)d_in[2];
    const float* Wt   = (const float*)d_in[3];
    float* out = (float*)d_out;

    char* ws = (char*)d_ws;
    ushort* xb  = (ushort*)(ws);
    ushort* dWv = (ushort*)(ws + 67108864);
    ushort* dWt = (ushort*)(ws + 69206016);
    int* V   = (int*)(ws + 71303168);
    int* T   = V + 32768;
    int* cnt = T + 32768;

    prep_kernel<<<4384, 1024, 0, stream>>>(x, mask, Wv, Wt, xb, dWv, dWt, V, T, cnt);
    // grid: bm = gk*8 + (blockIdx&7) must reach ~258 -> gk up to 32 -> 33*64 blocks
    gemm_kernel<<<33 * 64, 256, 0, stream>>>(xb, dWv, dWt, V, T, cnt, out);
}